// Round 2
// baseline (354.941 us; speedup 1.0000x reference)
//
#include <hip/hip_runtime.h>
#include <hip/hip_cooperative_groups.h>
#include <math.h>

namespace cg = cooperative_groups;

// ModifiedBarlowTwinsLoss — augmented-Gram formulation, bf16 MFMA.
// Y = [X | M] (M = one-hot labels, 128 padded classes). One MFMA pass gives:
//   X^T X  (10 upper 128x128 tiles)  -> Gram for term1 + column sumsq
//   X^T M  (4 tiles)                 -> per-class column sums R (term2, mu)
// loss = (1/D^2) sum Ga~ Gb~ - (2/D) sum_c Sa~·Sb~ + sum_c n_c^2
//
// R2: single cooperative megakernel (448 blocks, 4 grid syncs) replacing the
// 5-kernel chain — removes launch gaps, keeps part L2/L3-hot for the fold,
// moves the label histogram into phase 0. Verified 5-kernel path kept as a
// runtime fallback if cooperative launch is unavailable.

#define NN 8192
#define DD 512
#define NC 100
#define SPLITK 16
#define NXT 10            // X^T X upper-triangle tiles
#define NTILE 14          // + 4 X^T M tiles
#define GRID 448

// ws byte offsets
#define GA_B    0u           // 512*512*4
#define GB_B    1048576u
#define RTA_B   2097152u     // RT: [128 classes][512 cols] f32 = 262144 B
#define RTB_B   2359296u
#define MUA_B   2621440u
#define MUB_B   2623488u
#define RSA_B   2625536u
#define RSB_B   2627584u
#define CNT_B   2629632u
#define XTA_B   4194304u     // 512*8192*2
#define XTB_B   12582912u
#define MT_B    20971520u    // 128*8192*2
#define PART_B  23068672u    // 2*14*16*16384*4 = 29,360,128 (end ~52.4 MB)

typedef __attribute__((ext_vector_type(8))) short short8;
typedef __attribute__((ext_vector_type(4))) float f32x4;

__constant__ int c_ti[NTILE] = {0,0,0,0,1,1,1,2,2,3, 0,1,2,3};
__constant__ int c_tj[NTILE] = {0,1,2,3,1,2,3,2,3,3, 4,4,4,4};
__constant__ float c_w[NXT]  = {1.f,2.f,2.f,2.f,1.f,2.f,2.f,1.f,2.f,1.f};

#if defined(__has_builtin)
#if __has_builtin(__builtin_amdgcn_global_load_lds)
#define HAVE_GLL 1
#endif
#endif

#ifdef HAVE_GLL
__device__ __forceinline__ void async16(const void* g, void* l) {
    __builtin_amdgcn_global_load_lds(
        (const __attribute__((address_space(1))) void*)g,
        (__attribute__((address_space(3))) void*)l, 16, 0, 0);
}
#endif

__device__ __forceinline__ short f2bf_rne(float f) {
    unsigned int u = __builtin_bit_cast(unsigned int, f);
    u += 0x7fffu + ((u >> 16) & 1u);
    return (short)(u >> 16);
}

__device__ __forceinline__ float block_reduce_sum_p(float v, float* red) {
    int lane = threadIdx.x & 63;
    int wave = threadIdx.x >> 6;
    #pragma unroll
    for (int off = 32; off > 0; off >>= 1) v += __shfl_down(v, off, 64);
    if (lane == 0) red[wave] = v;
    __syncthreads();
    float s = 0.f;
    if (threadIdx.x == 0) {
        int nw = (blockDim.x + 63) >> 6;
        for (int w = 0; w < nw; w++) s += red[w];
    }
    return s; // thread 0 only
}

// ---------------------------------------------------------------------------
// Megakernel: P0 prep -> P1 gram -> P2 fold -> P3 stats -> P4 terms
// ---------------------------------------------------------------------------
__global__ __launch_bounds__(256, 2)
void k_mega(const float* __restrict__ A, const float* __restrict__ B,
            const int* __restrict__ labels,
            short* __restrict__ XTa, short* __restrict__ XTb,
            short* __restrict__ MT, float* __restrict__ part,
            float* __restrict__ Ga, float* __restrict__ Gb,
            float* __restrict__ RTa, float* __restrict__ RTb,
            float* __restrict__ mu_a, float* __restrict__ mu_b,
            float* __restrict__ rs_a, float* __restrict__ rs_b,
            int* __restrict__ counts, float* __restrict__ out) {
    __shared__ short LA[2][128 * 64];
    __shared__ short LB[2][128 * 64];
    __shared__ short LT[64][72];
    __shared__ int   hist[NC];
    __shared__ float red[8];

    cg::grid_group grid = cg::this_grid();
    int bid = blockIdx.x;
    int t = threadIdx.x;

    // ---------------- P0: transpose-convert + one-hot + histogram ----------
    for (int vb = bid; vb < 2177; vb += GRID) {
        if (vb >= 2048) {
            int c = vb - 2048;
            if (c == 128) {
                if (t < NC) hist[t] = 0;
                __syncthreads();
                for (int i = t; i < NN; i += 256) atomicAdd(&hist[labels[i]], 1);
                __syncthreads();
                if (t < NC) counts[t] = hist[t];
                if (t == 0) out[0] = 0.f;
            } else {
                unsigned short one = 0x3F80; // bf16 1.0
                ushort4* dst = (ushort4*)(MT + (size_t)c * NN);
                const int4* lb4 = (const int4*)labels;
                #pragma unroll
                for (int j = 0; j < 8; j++) {
                    int i4 = j * 256 + t;
                    int4 lb = lb4[i4];
                    ushort4 v;
                    v.x = (lb.x == c) ? one : (unsigned short)0;
                    v.y = (lb.y == c) ? one : (unsigned short)0;
                    v.z = (lb.z == c) ? one : (unsigned short)0;
                    v.w = (lb.w == c) ? one : (unsigned short)0;
                    dst[i4] = v;
                }
            }
        } else {
            __syncthreads();   // protect LT reuse across vb iterations
            const float* X = (vb >> 10) ? B : A;
            short* XT = (vb >> 10) ? XTb : XTa;
            int rem = vb & 1023;
            int c0 = (rem >> 7) << 6;
            int k0 = (rem & 127) << 6;
            int cc = t & 15;
            int kb = t >> 4;
            #pragma unroll
            for (int s = 0; s < 4; s++) {
                int kr = kb + s * 16;
                float4 v = *(const float4*)&X[(size_t)(k0 + kr) * DD + c0 + cc * 4];
                LT[cc * 4 + 0][kr] = f2bf_rne(v.x);
                LT[cc * 4 + 1][kr] = f2bf_rne(v.y);
                LT[cc * 4 + 2][kr] = f2bf_rne(v.z);
                LT[cc * 4 + 3][kr] = f2bf_rne(v.w);
            }
            __syncthreads();
            #pragma unroll
            for (int s = 0; s < 2; s++) {
                int idx = s * 256 + t;
                int orow = idx >> 3;
                int och = idx & 7;
                *(uint4*)&XT[(size_t)(c0 + orow) * NN + k0 + och * 8] =
                    *(const uint4*)&LT[orow][och * 8];
            }
        }
    }

    grid.sync();

    // ---------------- P1: bf16 MFMA augmented Gram (split-K) ---------------
    {
        int b = bid;                     // 0..447
        int xcd = b & 7;
        int idx = b >> 3;                // 0..55
        int grp = (idx / NTILE) * 8 + xcd;   // (mat,chunk) group, 0..31
        int tile = idx % NTILE;
        int mat = grp >> 4;
        int chunk = grp & 15;

        const short* XT = mat ? XTb : XTa;
        int ti = c_ti[tile], tj = c_tj[tile];
        const short* PA = XT + (size_t)ti * 128 * NN;
        const short* PB = (tj < 4) ? (XT + (size_t)tj * 128 * NN) : MT;
        int k0 = chunk * (NN / SPLITK);

        int wave = t >> 6, lane = t & 63;
        int quad = lane >> 4, l16 = lane & 15;
        int x7 = l16 & 7;
        int wrow = (wave >> 1) * 64, wcol = (wave & 1) * 64;

        int srow = lane >> 3;                 // row within 8-row segment
        int sc = (lane & 7) ^ srow;           // swizzled global 16B-chunk index

        auto stage = [&](int buf, int kk) {
            #pragma unroll
            for (int rr = 0; rr < 4; rr++) {
                int seg = wave * 4 + rr;
                int row = seg * 8 + srow;
                const short* ga = PA + (size_t)row * NN + k0 + kk + sc * 8;
                const short* gb = PB + (size_t)row * NN + k0 + kk + sc * 8;
#ifdef HAVE_GLL
                async16(ga, &LA[buf][seg * 512]);
                async16(gb, &LB[buf][seg * 512]);
#else
                *(uint4*)&LA[buf][seg * 512 + lane * 8] = *(const uint4*)ga;
                *(uint4*)&LB[buf][seg * 512 + lane * 8] = *(const uint4*)gb;
#endif
            }
        };

        f32x4 acc[4][4];
        #pragma unroll
        for (int i = 0; i < 4; i++)
            #pragma unroll
            for (int j = 0; j < 4; j++) acc[i][j] = (f32x4)0.f;

        const int KR = NN / SPLITK;           // 512
        int cur = 0;
        stage(0, 0);
        __syncthreads();                      // drains vmcnt(0): buf0 ready

        for (int kk = 0; kk < KR; kk += 64) {
            if (kk + 64 < KR) stage(cur ^ 1, kk + 64);  // prefetch next step
            #pragma unroll
            for (int ks = 0; ks < 2; ks++) {
                short8 a[4], bfr[4];
                #pragma unroll
                for (int mt = 0; mt < 4; mt++)
                    a[mt] = *(const short8*)&LA[cur][(wrow + mt * 16 + l16) * 64 +
                                                     (((ks * 4 + quad) ^ x7) << 3)];
                #pragma unroll
                for (int nt = 0; nt < 4; nt++)
                    bfr[nt] = *(const short8*)&LB[cur][(wcol + nt * 16 + l16) * 64 +
                                                       (((ks * 4 + quad) ^ x7) << 3)];
                #pragma unroll
                for (int mt = 0; mt < 4; mt++)
                    #pragma unroll
                    for (int nt = 0; nt < 4; nt++)
                        acc[mt][nt] = __builtin_amdgcn_mfma_f32_16x16x32_bf16(
                            a[mt], bfr[nt], acc[mt][nt], 0, 0, 0);
            }
            __syncthreads();   // next buffer staged; cur reads done
            cur ^= 1;
        }

        float* pbase = part + ((size_t)(mat * NTILE + tile) * SPLITK + chunk) * 16384;
        #pragma unroll
        for (int mt = 0; mt < 4; mt++)
            #pragma unroll
            for (int nt = 0; nt < 4; nt++)
                #pragma unroll
                for (int rj = 0; rj < 4; rj++) {
                    int rr2 = wrow + mt * 16 + quad * 4 + rj;
                    int cc2 = wcol + nt * 16 + l16;
                    pbase[rr2 * 128 + cc2] = acc[mt][nt][rj];
                }
    }

    grid.sync();

    // ---------------- P2: fold SPLITK partials -> G / RT -------------------
    {
        int mat = bid / (NTILE * 16);
        int rr = bid % (NTILE * 16);
        int tile = rr / 16;
        int e4 = (rr % 16) * 1024 + t * 4;
        const float4* p = (const float4*)(part +
            (size_t)(mat * NTILE + tile) * SPLITK * 16384 + e4);
        float4 s = make_float4(0.f, 0.f, 0.f, 0.f);
        #pragma unroll
        for (int c = 0; c < SPLITK; c++) {
            float4 v = p[(size_t)c * 4096];
            s.x += v.x; s.y += v.y; s.z += v.z; s.w += v.w;
        }
        int rw = e4 >> 7, cl = e4 & 127;
        if (tile < NXT) {
            float* G = mat ? Gb : Ga;
            *(float4*)&G[(c_ti[tile] * 128 + rw) * DD + c_tj[tile] * 128 + cl] = s;
        } else {
            float* RT = mat ? RTb : RTa;
            int col = (tile - NXT) * 128 + rw;     // [class][col]
            RT[(size_t)(cl + 0) * DD + col] = s.x;
            RT[(size_t)(cl + 1) * DD + col] = s.y;
            RT[(size_t)(cl + 2) * DD + col] = s.z;
            RT[(size_t)(cl + 3) * DD + col] = s.w;
        }
    }

    grid.sync();

    // ---------------- P3: column stats (2 blocks) --------------------------
    if (bid < 2) {
        int mat = bid;
        const float* RT = mat ? RTb : RTa;
        const float* G = mat ? Gb : Ga;
        for (int k = t; k < DD; k += 256) {
            float s = 0.f;
            for (int c = 0; c < 128; c++) s += RT[c * DD + k];
            float mu = s / (float)NN;
            float sumsq = G[k * DD + k];
            float var = (sumsq - (float)NN * mu * mu) / (float)(NN - 1);
            (mat ? mu_b : mu_a)[k] = mu;
            (mat ? rs_b : rs_a)[k] = rsqrtf(var);
        }
    }

    grid.sync();

    // ---------------- P4: loss terms ---------------------------------------
    if (bid < 256) {
        float local = 0.f;
        for (int x = bid * 256 + t; x < NXT * 16384; x += 256 * 256) {
            int tile = x >> 14, e = x & 16383;
            int gi = c_ti[tile] * 128 + (e >> 7);
            int gj = c_tj[tile] * 128 + (e & 127);
            float ga = rs_a[gi] * rs_a[gj] * (Ga[gi * DD + gj] - (float)NN * mu_a[gi] * mu_a[gj]);
            float gb = rs_b[gi] * rs_b[gj] * (Gb[gi * DD + gj] - (float)NN * mu_b[gi] * mu_b[gj]);
            local += c_w[tile] * ga * gb;
        }
        float s = block_reduce_sum_p(local, red);
        if (t == 0) atomicAdd(out, s * (1.0f / ((float)DD * (float)DD)));
    } else if (bid < 356) {
        int c = bid - 256;
        float n = (float)counts[c];
        float local = 0.f;
        for (int k = t; k < DD; k += 256) {
            float ta = rs_a[k] * (RTa[c * DD + k] - n * mu_a[k]);
            float tb = rs_b[k] * (RTb[c * DD + k] - n * mu_b[k]);
            local += ta * tb;
        }
        float s = block_reduce_sum_p(local, red);
        if (t == 0) {
            float add = s * (-2.0f / (float)DD);
            if (c == 0) {
                float t3 = 0.f;
                for (int cc = 0; cc < NC; cc++) {
                    float nc = (float)counts[cc];
                    t3 += nc * nc;
                }
                add += t3;
            }
            atomicAdd(out, add);
        }
    }
}

// ---------------------------------------------------------------------------
// Fallback path: the R1-verified 5-kernel chain (used only if cooperative
// launch is unavailable on this runtime).
// ---------------------------------------------------------------------------
__global__ __launch_bounds__(256) void k_prep(const float* __restrict__ A,
                                              const float* __restrict__ B,
                                              const int* __restrict__ labels,
                                              short* __restrict__ XTa,
                                              short* __restrict__ XTb,
                                              short* __restrict__ MT,
                                              float* __restrict__ out) {
    __shared__ short LT[64][72];
    int bid = blockIdx.x;
    int t = threadIdx.x;

    if (bid >= 2048) {
        int c = bid - 2048;
        if (c == 128) { if (t == 0) out[0] = 0.f; return; }
        unsigned short one = 0x3F80;
        ushort4* dst = (ushort4*)(MT + (size_t)c * NN);
        const int4* lb4 = (const int4*)labels;
        #pragma unroll
        for (int j = 0; j < 8; j++) {
            int i4 = j * 256 + t;
            int4 lb = lb4[i4];
            ushort4 v;
            v.x = (lb.x == c) ? one : (unsigned short)0;
            v.y = (lb.y == c) ? one : (unsigned short)0;
            v.z = (lb.z == c) ? one : (unsigned short)0;
            v.w = (lb.w == c) ? one : (unsigned short)0;
            dst[i4] = v;
        }
        return;
    }

    const float* X = (bid >> 10) ? B : A;
    short* XT = (bid >> 10) ? XTb : XTa;
    int rem = bid & 1023;
    int c0 = (rem >> 7) << 6;
    int k0 = (rem & 127) << 6;
    int cc = t & 15;
    int kb = t >> 4;
    #pragma unroll
    for (int s = 0; s < 4; s++) {
        int kr = kb + s * 16;
        float4 v = *(const float4*)&X[(size_t)(k0 + kr) * DD + c0 + cc * 4];
        LT[cc * 4 + 0][kr] = f2bf_rne(v.x);
        LT[cc * 4 + 1][kr] = f2bf_rne(v.y);
        LT[cc * 4 + 2][kr] = f2bf_rne(v.z);
        LT[cc * 4 + 3][kr] = f2bf_rne(v.w);
    }
    __syncthreads();
    #pragma unroll
    for (int s = 0; s < 2; s++) {
        int idx = s * 256 + t;
        int orow = idx >> 3;
        int och = idx & 7;
        *(uint4*)&XT[(size_t)(c0 + orow) * NN + k0 + och * 8] =
            *(const uint4*)&LT[orow][och * 8];
    }
}

__global__ __launch_bounds__(256, 2) void k_gram(const short* __restrict__ XTa,
                                                 const short* __restrict__ XTb,
                                                 const short* __restrict__ MT,
                                                 float* __restrict__ part) {
    __shared__ short LA[2][128 * 64];
    __shared__ short LB[2][128 * 64];

    int b = blockIdx.x;
    int xcd = b & 7;
    int idx = b >> 3;
    int grp = (idx / NTILE) * 8 + xcd;
    int tile = idx % NTILE;
    int mat = grp >> 4;
    int chunk = grp & 15;

    const short* XT = mat ? XTb : XTa;
    int ti = c_ti[tile], tj = c_tj[tile];
    const short* PA = XT + (size_t)ti * 128 * NN;
    const short* PB = (tj < 4) ? (XT + (size_t)tj * 128 * NN) : MT;
    int k0 = chunk * (NN / SPLITK);

    int t = threadIdx.x;
    int wave = t >> 6, lane = t & 63;
    int quad = lane >> 4, l16 = lane & 15;
    int x7 = l16 & 7;
    int wrow = (wave >> 1) * 64, wcol = (wave & 1) * 64;
    int srow = lane >> 3;
    int sc = (lane & 7) ^ srow;

    auto stage = [&](int buf, int kk) {
        #pragma unroll
        for (int rr = 0; rr < 4; rr++) {
            int seg = wave * 4 + rr;
            int row = seg * 8 + srow;
            const short* ga = PA + (size_t)row * NN + k0 + kk + sc * 8;
            const short* gb = PB + (size_t)row * NN + k0 + kk + sc * 8;
#ifdef HAVE_GLL
            async16(ga, &LA[buf][seg * 512]);
            async16(gb, &LB[buf][seg * 512]);
#else
            *(uint4*)&LA[buf][seg * 512 + lane * 8] = *(const uint4*)ga;
            *(uint4*)&LB[buf][seg * 512 + lane * 8] = *(const uint4*)gb;
#endif
        }
    };

    f32x4 acc[4][4];
    #pragma unroll
    for (int i = 0; i < 4; i++)
        #pragma unroll
        for (int j = 0; j < 4; j++) acc[i][j] = (f32x4)0.f;

    const int KR = NN / SPLITK;
    int cur = 0;
    stage(0, 0);
    __syncthreads();

    for (int kk = 0; kk < KR; kk += 64) {
        if (kk + 64 < KR) stage(cur ^ 1, kk + 64);
        #pragma unroll
        for (int ks = 0; ks < 2; ks++) {
            short8 a[4], bfr[4];
            #pragma unroll
            for (int mt = 0; mt < 4; mt++)
                a[mt] = *(const short8*)&LA[cur][(wrow + mt * 16 + l16) * 64 +
                                                 (((ks * 4 + quad) ^ x7) << 3)];
            #pragma unroll
            for (int nt = 0; nt < 4; nt++)
                bfr[nt] = *(const short8*)&LB[cur][(wcol + nt * 16 + l16) * 64 +
                                                   (((ks * 4 + quad) ^ x7) << 3)];
            #pragma unroll
            for (int mt = 0; mt < 4; mt++)
                #pragma unroll
                for (int nt = 0; nt < 4; nt++)
                    acc[mt][nt] = __builtin_amdgcn_mfma_f32_16x16x32_bf16(
                        a[mt], bfr[nt], acc[mt][nt], 0, 0, 0);
        }
        __syncthreads();
        cur ^= 1;
    }

    float* pbase = part + ((size_t)(mat * NTILE + tile) * SPLITK + chunk) * 16384;
    #pragma unroll
    for (int mt = 0; mt < 4; mt++)
        #pragma unroll
        for (int nt = 0; nt < 4; nt++)
            #pragma unroll
            for (int rj = 0; rj < 4; rj++) {
                int rr2 = wrow + mt * 16 + quad * 4 + rj;
                int cc2 = wcol + nt * 16 + l16;
                pbase[rr2 * 128 + cc2] = acc[mt][nt][rj];
            }
}

__global__ void k_gsum(const float* __restrict__ part,
                       float* __restrict__ Ga, float* __restrict__ Gb,
                       float* __restrict__ RTa, float* __restrict__ RTb) {
    int bid = blockIdx.x;
    int mat = bid / (NTILE * 16);
    int rr = bid % (NTILE * 16);
    int tile = rr / 16;
    int e4 = (rr % 16) * 1024 + threadIdx.x * 4;
    const float4* p = (const float4*)(part +
        (size_t)(mat * NTILE + tile) * SPLITK * 16384 + e4);
    float4 s = make_float4(0.f, 0.f, 0.f, 0.f);
    #pragma unroll
    for (int c = 0; c < SPLITK; c++) {
        float4 v = p[(size_t)c * 4096];
        s.x += v.x; s.y += v.y; s.z += v.z; s.w += v.w;
    }
    int rw = e4 >> 7, cl = e4 & 127;
    if (tile < NXT) {
        float* G = mat ? Gb : Ga;
        *(float4*)&G[(c_ti[tile] * 128 + rw) * DD + c_tj[tile] * 128 + cl] = s;
    } else {
        float* RT = mat ? RTb : RTa;
        int col = (tile - NXT) * 128 + rw;
        RT[(size_t)(cl + 0) * DD + col] = s.x;
        RT[(size_t)(cl + 1) * DD + col] = s.y;
        RT[(size_t)(cl + 2) * DD + col] = s.z;
        RT[(size_t)(cl + 3) * DD + col] = s.w;
    }
}

__global__ void k_stats(const float* __restrict__ Ga, const float* __restrict__ Gb,
                        const float* __restrict__ RTa, const float* __restrict__ RTb,
                        const int* __restrict__ labels,
                        float* mu_a, float* mu_b, float* rs_a, float* rs_b,
                        int* counts) {
    if (blockIdx.x == 2) {
        __shared__ int h[NC];
        int t = threadIdx.x;
        if (t < NC) h[t] = 0;
        __syncthreads();
        for (int i = t; i < NN; i += blockDim.x) atomicAdd(&h[labels[i]], 1);
        __syncthreads();
        if (t < NC) counts[t] = h[t];
        return;
    }
    int mat = blockIdx.x;
    int k = threadIdx.x;
    const float* RT = mat ? RTb : RTa;
    const float* G = mat ? Gb : Ga;
    float s = 0.f;
    for (int c = 0; c < 128; c++) s += RT[c * DD + k];
    float mu = s / (float)NN;
    float sumsq = G[k * DD + k];
    float var = (sumsq - (float)NN * mu * mu) / (float)(NN - 1);
    (mat ? mu_b : mu_a)[k] = mu;
    (mat ? rs_b : rs_a)[k] = rsqrtf(var);
}

__global__ void k_term(const float* __restrict__ Ga, const float* __restrict__ Gb,
                       const float* __restrict__ RTa, const float* __restrict__ RTb,
                       const float* __restrict__ mu_a, const float* __restrict__ mu_b,
                       const float* __restrict__ rs_a, const float* __restrict__ rs_b,
                       const int* __restrict__ counts, float* out) {
    __shared__ float red[8];
    int bid = blockIdx.x;
    if (bid < 256) {
        float local = 0.f;
        for (int x = bid * 256 + threadIdx.x; x < NXT * 16384; x += 256 * 256) {
            int tile = x >> 14, e = x & 16383;
            int gi = c_ti[tile] * 128 + (e >> 7);
            int gj = c_tj[tile] * 128 + (e & 127);
            float ga = rs_a[gi] * rs_a[gj] * (Ga[gi * DD + gj] - (float)NN * mu_a[gi] * mu_a[gj]);
            float gb = rs_b[gi] * rs_b[gj] * (Gb[gi * DD + gj] - (float)NN * mu_b[gi] * mu_b[gj]);
            local += c_w[tile] * ga * gb;
        }
        float s = block_reduce_sum_p(local, red);
        if (threadIdx.x == 0) atomicAdd(out, s * (1.0f / ((float)DD * (float)DD)));
    } else {
        int c = bid - 256;
        float n = (float)counts[c];
        float local = 0.f;
        for (int k = threadIdx.x; k < DD; k += 256) {
            float ta = rs_a[k] * (RTa[c * DD + k] - n * mu_a[k]);
            float tb = rs_b[k] * (RTb[c * DD + k] - n * mu_b[k]);
            local += ta * tb;
        }
        float s = block_reduce_sum_p(local, red);
        if (threadIdx.x == 0) {
            float add = s * (-2.0f / (float)DD);
            if (c == 0) {
                float t3 = 0.f;
                for (int cc = 0; cc < NC; cc++) {
                    float nc = (float)counts[cc];
                    t3 += nc * nc;
                }
                add += t3;
            }
            atomicAdd(out, add);
        }
    }
}

extern "C" void kernel_launch(void* const* d_in, const int* in_sizes, int n_in,
                              void* d_out, int out_size, void* d_ws, size_t ws_size,
                              hipStream_t stream) {
    const float* z_a = (const float*)d_in[0];
    const float* z_b = (const float*)d_in[1];
    const int* labels = (const int*)d_in[2];
    float* out = (float*)d_out;
    char* wsb = (char*)d_ws;

    float* Ga = (float*)(wsb + GA_B);
    float* Gb = (float*)(wsb + GB_B);
    float* RTa = (float*)(wsb + RTA_B);
    float* RTb = (float*)(wsb + RTB_B);
    float* mu_a = (float*)(wsb + MUA_B);
    float* mu_b = (float*)(wsb + MUB_B);
    float* rs_a = (float*)(wsb + RSA_B);
    float* rs_b = (float*)(wsb + RSB_B);
    int* counts = (int*)(wsb + CNT_B);
    short* XTa = (short*)(wsb + XTA_B);
    short* XTb = (short*)(wsb + XTB_B);
    short* MT = (short*)(wsb + MT_B);
    float* part = (float*)(wsb + PART_B);

    void* args[] = {
        (void*)&z_a, (void*)&z_b, (void*)&labels,
        (void*)&XTa, (void*)&XTb, (void*)&MT, (void*)&part,
        (void*)&Ga, (void*)&Gb, (void*)&RTa, (void*)&RTb,
        (void*)&mu_a, (void*)&mu_b, (void*)&rs_a, (void*)&rs_b,
        (void*)&counts, (void*)&out
    };
    hipError_t e = hipLaunchCooperativeKernel((const void*)k_mega,
                                              dim3(GRID), dim3(256),
                                              args, 0, stream);
    if (e != hipSuccess) {
        (void)hipGetLastError();   // clear sticky error, use verified fallback
        hipLaunchKernelGGL(k_prep, dim3(2177), dim3(256), 0, stream,
                           z_a, z_b, labels, XTa, XTb, MT, out);
        hipLaunchKernelGGL(k_gram, dim3(2 * NTILE * SPLITK), dim3(256), 0, stream,
                           XTa, XTb, MT, part);
        hipLaunchKernelGGL(k_gsum, dim3(2 * NTILE * 16), dim3(256), 0, stream,
                           part, Ga, Gb, RTa, RTb);
        hipLaunchKernelGGL(k_stats, dim3(3), dim3(512), 0, stream,
                           Ga, Gb, RTa, RTb, labels, mu_a, mu_b, rs_a, rs_b, counts);
        hipLaunchKernelGGL(k_term, dim3(356), dim3(256), 0, stream,
                           Ga, Gb, RTa, RTb, mu_a, mu_b, rs_a, rs_b, counts, out);
    }
}

// Round 3
// 147.894 us; speedup vs baseline: 2.4000x; 2.4000x over previous
//
#include <hip/hip_runtime.h>
#include <math.h>

// ModifiedBarlowTwinsLoss — augmented-Gram formulation, bf16 MFMA.
// Y = [X | M] (M = one-hot labels, 128 padded classes). One MFMA pass gives:
//   X^T X  (10 upper 128x128 tiles)  -> Gram for term1 + column sumsq
//   X^T M  (4 tiles)                 -> per-class column sums R (term2, mu)
// loss = (1/D^2) sum Ga~ Gb~ - (2/D) sum_c Sa~·Sb~ + sum_c n_c^2
//
// R3 (post megakernel-regression revert): back to multi-kernel chain, but
//  - part/k_gsum ELIMINATED: k_gram atomic-folds split-K partials straight
//    into G (f32 atomicAdd; target 2.36 MB, L2-resident) and RT stored
//    transposed R2[col][class] so all atomics are 16-consecutive coalesced.
//  - k_stats ELIMINATED: k_term recomputes mu/rs per block into LDS
//    (512 KB L2-hot reads/block — cheaper than a launch boundary).
//  - G/R2 zero + histogram folded into k_prep's grid.
//  Chain: k_prep(2257) -> k_gram(448) -> k_term(228). 3 launches.
// Lesson from R2: cg::grid.sync() costs ~50 µs/sync at 448 blocks — never
// use cooperative sync here.

#define NN 8192
#define DD 512
#define NC 100
#define SPLITK 16
#define NXT 10            // X^T X upper-triangle tiles
#define NTILE 14          // + 4 X^T M tiles

// ws byte offsets (GA,GB,R2A,R2B contiguous: zeroed as one 2.5 MB span)
#define GA_B    0u           // 512*512*4 = 1 MB
#define GB_B    1048576u
#define R2A_B   2097152u     // R2: [512 cols][128 classes] f32 = 256 KB
#define R2B_B   2359296u
#define ZERO_END 2621440u
#define CNT_B   2621440u
#define XTA_B   4194304u     // 512*8192*2
#define XTB_B   12582912u
#define MT_B    20971520u    // 128*8192*2 (end ~23 MB)

typedef __attribute__((ext_vector_type(8))) short short8;
typedef __attribute__((ext_vector_type(4))) float f32x4;

__constant__ int c_ti[NTILE] = {0,0,0,0,1,1,1,2,2,3, 0,1,2,3};
__constant__ int c_tj[NTILE] = {0,1,2,3,1,2,3,2,3,3, 4,4,4,4};
__constant__ float c_w[NXT]  = {1.f,2.f,2.f,2.f,1.f,2.f,2.f,1.f,2.f,1.f};

#if defined(__has_builtin)
#if __has_builtin(__builtin_amdgcn_global_load_lds)
#define HAVE_GLL 1
#endif
#endif

#ifdef HAVE_GLL
__device__ __forceinline__ void async16(const void* g, void* l) {
    __builtin_amdgcn_global_load_lds(
        (const __attribute__((address_space(1))) void*)g,
        (__attribute__((address_space(3))) void*)l, 16, 0, 0);
}
#endif

__device__ __forceinline__ short f2bf_rne(float f) {
    unsigned int u = __builtin_bit_cast(unsigned int, f);
    u += 0x7fffu + ((u >> 16) & 1u);
    return (short)(u >> 16);
}

__device__ __forceinline__ float block_reduce_sum_p(float v, float* red) {
    int lane = threadIdx.x & 63;
    int wave = threadIdx.x >> 6;
    #pragma unroll
    for (int off = 32; off > 0; off >>= 1) v += __shfl_down(v, off, 64);
    if (lane == 0) red[wave] = v;
    __syncthreads();
    float s = 0.f;
    if (threadIdx.x == 0) {
        int nw = (blockDim.x + 63) >> 6;
        for (int w = 0; w < nw; w++) s += red[w];
    }
    return s; // thread 0 only
}

// K1: blocks 0..2047 transpose-convert f32->bf16; 2048..2175 one-hot MT;
//     2176..2255 zero G/R2 span; 2256 histogram + out-zero.
__global__ __launch_bounds__(256) void k_prep(const float* __restrict__ A,
                                              const float* __restrict__ B,
                                              const int* __restrict__ labels,
                                              short* __restrict__ XTa,
                                              short* __restrict__ XTb,
                                              short* __restrict__ MT,
                                              float* __restrict__ zero_span,
                                              int* __restrict__ counts,
                                              float* __restrict__ out) {
    __shared__ short LT[64][72];
    __shared__ int hist[NC];
    int bid = blockIdx.x;
    int t = threadIdx.x;

    if (bid >= 2048) {
        if (bid >= 2256) {              // histogram + out zero
            if (t < NC) hist[t] = 0;
            __syncthreads();
            for (int i = t; i < NN; i += 256) atomicAdd(&hist[labels[i]], 1);
            __syncthreads();
            if (t < NC) counts[t] = hist[t];
            if (t == 0) out[0] = 0.f;
            return;
        }
        if (bid >= 2176) {              // zero G/R2: 80 blocks x 32 KB
            int zb = bid - 2176;
            float4* dst = (float4*)zero_span;
            float4 z = make_float4(0.f, 0.f, 0.f, 0.f);
            #pragma unroll
            for (int j = 0; j < 8; j++) dst[zb * 2048 + j * 256 + t] = z;
            return;
        }
        int c = bid - 2048;             // one-hot MT row
        unsigned short one = 0x3F80;    // bf16 1.0
        ushort4* dst = (ushort4*)(MT + (size_t)c * NN);
        const int4* lb4 = (const int4*)labels;
        #pragma unroll
        for (int j = 0; j < 8; j++) {
            int i4 = j * 256 + t;
            int4 lb = lb4[i4];
            ushort4 v;
            v.x = (lb.x == c) ? one : (unsigned short)0;
            v.y = (lb.y == c) ? one : (unsigned short)0;
            v.z = (lb.z == c) ? one : (unsigned short)0;
            v.w = (lb.w == c) ? one : (unsigned short)0;
            dst[i4] = v;
        }
        return;
    }

    const float* X = (bid >> 10) ? B : A;
    short* XT = (bid >> 10) ? XTb : XTa;
    int rem = bid & 1023;
    int c0 = (rem >> 7) << 6;
    int k0 = (rem & 127) << 6;
    int cc = t & 15;
    int kb = t >> 4;
    #pragma unroll
    for (int s = 0; s < 4; s++) {
        int kr = kb + s * 16;
        float4 v = *(const float4*)&X[(size_t)(k0 + kr) * DD + c0 + cc * 4];
        LT[cc * 4 + 0][kr] = f2bf_rne(v.x);
        LT[cc * 4 + 1][kr] = f2bf_rne(v.y);
        LT[cc * 4 + 2][kr] = f2bf_rne(v.z);
        LT[cc * 4 + 3][kr] = f2bf_rne(v.w);
    }
    __syncthreads();
    #pragma unroll
    for (int s = 0; s < 2; s++) {
        int idx = s * 256 + t;
        int orow = idx >> 3;
        int och = idx & 7;
        *(uint4*)&XT[(size_t)(c0 + orow) * NN + k0 + och * 8] =
            *(const uint4*)&LT[orow][och * 8];
    }
}

// K2: bf16 MFMA augmented Gram. 448 blocks = 2 mats x 14 tiles x 16 K-chunks.
// Double-buffered LDS; XOR-swizzled; XCD-grouped (all 14 tiles of one
// (mat,chunk) share an XCD's L2). Split-K folded via coalesced f32 atomicAdd
// directly into G / R2 (no `part` intermediate).
__global__ __launch_bounds__(256, 2) void k_gram(const short* __restrict__ XTa,
                                                 const short* __restrict__ XTb,
                                                 const short* __restrict__ MT,
                                                 float* __restrict__ Ga,
                                                 float* __restrict__ Gb,
                                                 float* __restrict__ R2a,
                                                 float* __restrict__ R2b) {
    __shared__ short LA[2][128 * 64];
    __shared__ short LB[2][128 * 64];

    int b = blockIdx.x;              // 0..447
    int xcd = b & 7;
    int idx = b >> 3;                // 0..55
    int grp = (idx / NTILE) * 8 + xcd;   // (mat,chunk) group, 0..31
    int tile = idx % NTILE;
    int mat = grp >> 4;
    int chunk = grp & 15;

    const short* XT = mat ? XTb : XTa;
    int ti = c_ti[tile], tj = c_tj[tile];
    const short* PA = XT + (size_t)ti * 128 * NN;
    const short* PB = (tj < 4) ? (XT + (size_t)tj * 128 * NN) : MT;
    int k0 = chunk * (NN / SPLITK);

    int t = threadIdx.x;
    int wave = t >> 6, lane = t & 63;
    int quad = lane >> 4, l16 = lane & 15;
    int x7 = l16 & 7;
    int wrow = (wave >> 1) * 64, wcol = (wave & 1) * 64;

    int srow = lane >> 3;                 // row within 8-row segment
    int sc = (lane & 7) ^ srow;           // swizzled global 16B-chunk index

    auto stage = [&](int buf, int kk) {
        #pragma unroll
        for (int rr = 0; rr < 4; rr++) {
            int seg = wave * 4 + rr;
            int row = seg * 8 + srow;
            const short* ga = PA + (size_t)row * NN + k0 + kk + sc * 8;
            const short* gb = PB + (size_t)row * NN + k0 + kk + sc * 8;
#ifdef HAVE_GLL
            async16(ga, &LA[buf][seg * 512]);
            async16(gb, &LB[buf][seg * 512]);
#else
            *(uint4*)&LA[buf][seg * 512 + lane * 8] = *(const uint4*)ga;
            *(uint4*)&LB[buf][seg * 512 + lane * 8] = *(const uint4*)gb;
#endif
        }
    };

    f32x4 acc[4][4];
    #pragma unroll
    for (int i = 0; i < 4; i++)
        #pragma unroll
        for (int j = 0; j < 4; j++) acc[i][j] = (f32x4)0.f;

    const int KR = NN / SPLITK;           // 512
    int cur = 0;
    stage(0, 0);
    __syncthreads();                      // drains vmcnt(0): buf0 ready

    for (int kk = 0; kk < KR; kk += 64) {
        if (kk + 64 < KR) stage(cur ^ 1, kk + 64);  // prefetch next step
        #pragma unroll
        for (int ks = 0; ks < 2; ks++) {
            short8 a[4], bfr[4];
            #pragma unroll
            for (int mt = 0; mt < 4; mt++)
                a[mt] = *(const short8*)&LA[cur][(wrow + mt * 16 + l16) * 64 +
                                                 (((ks * 4 + quad) ^ x7) << 3)];
            #pragma unroll
            for (int nt = 0; nt < 4; nt++)
                bfr[nt] = *(const short8*)&LB[cur][(wcol + nt * 16 + l16) * 64 +
                                                   (((ks * 4 + quad) ^ x7) << 3)];
            #pragma unroll
            for (int mt = 0; mt < 4; mt++)
                #pragma unroll
                for (int nt = 0; nt < 4; nt++)
                    acc[mt][nt] = __builtin_amdgcn_mfma_f32_16x16x32_bf16(
                        a[mt], bfr[nt], acc[mt][nt], 0, 0, 0);
        }
        __syncthreads();   // next buffer staged; cur reads done
        cur ^= 1;
    }

    // Split-K fold: coalesced atomicAdd. XX tiles -> G[row][col];
    // XM tiles -> R2[col][class] (transposed so class varies with l16).
    if (tile < NXT) {
        float* G = (mat ? Gb : Ga) + ((size_t)ti * 128) * DD + tj * 128;
        #pragma unroll
        for (int mt = 0; mt < 4; mt++)
            #pragma unroll
            for (int nt = 0; nt < 4; nt++)
                #pragma unroll
                for (int rj = 0; rj < 4; rj++) {
                    int rr2 = wrow + mt * 16 + quad * 4 + rj;
                    int cc2 = wcol + nt * 16 + l16;
                    atomicAdd(&G[(size_t)rr2 * DD + cc2], acc[mt][nt][rj]);
                }
    } else {
        float* R = (mat ? R2b : R2a) + (size_t)(tile - NXT) * 128 * 128;
        #pragma unroll
        for (int mt = 0; mt < 4; mt++)
            #pragma unroll
            for (int nt = 0; nt < 4; nt++)
                #pragma unroll
                for (int rj = 0; rj < 4; rj++) {
                    int rr2 = wrow + mt * 16 + quad * 4 + rj;   // col in panel
                    int cc2 = wcol + nt * 16 + l16;             // class
                    atomicAdd(&R[(size_t)rr2 * 128 + cc2], acc[mt][nt][rj]);
                }
    }
}

// K3: per-block stats preamble (mu/rs -> LDS, L2-hot reads), then
//     blocks 0..127: term1 over stored tiles; 128..227: term2 per class
//     (block 128 also adds term3).
__global__ __launch_bounds__(256) void k_term(const float* __restrict__ Ga,
                                              const float* __restrict__ Gb,
                                              const float* __restrict__ R2a,
                                              const float* __restrict__ R2b,
                                              const int* __restrict__ counts,
                                              float* __restrict__ out) {
    __shared__ float smua[DD], smub[DD], srsa[DD], srsb[DD];
    __shared__ float red[8];
    int bid = blockIdx.x;
    int t = threadIdx.x;

    // stats: each thread covers cols t and t+256
    #pragma unroll
    for (int half = 0; half < 2; half++) {
        int k = half * 256 + t;
        float sa = 0.f, sb = 0.f;
        #pragma unroll 4
        for (int c = 0; c < 128; c++) {
            sa += R2a[(size_t)k * 128 + c];
            sb += R2b[(size_t)k * 128 + c];
        }
        float mua = sa * (1.0f / (float)NN);
        float mub = sb * (1.0f / (float)NN);
        float va = (Ga[(size_t)k * DD + k] - (float)NN * mua * mua) / (float)(NN - 1);
        float vb = (Gb[(size_t)k * DD + k] - (float)NN * mub * mub) / (float)(NN - 1);
        smua[k] = mua; smub[k] = mub;
        srsa[k] = rsqrtf(va); srsb[k] = rsqrtf(vb);
    }
    __syncthreads();

    if (bid < 128) {
        float local = 0.f;
        for (int x = bid * 256 + t; x < NXT * 16384; x += 128 * 256) {
            int tile = x >> 14, e = x & 16383;
            int gi = c_ti[tile] * 128 + (e >> 7);
            int gj = c_tj[tile] * 128 + (e & 127);
            float ga = srsa[gi] * srsa[gj] *
                       (Ga[(size_t)gi * DD + gj] - (float)NN * smua[gi] * smua[gj]);
            float gb = srsb[gi] * srsb[gj] *
                       (Gb[(size_t)gi * DD + gj] - (float)NN * smub[gi] * smub[gj]);
            local += c_w[tile] * ga * gb;
        }
        float s = block_reduce_sum_p(local, red);
        if (t == 0) atomicAdd(out, s * (1.0f / ((float)DD * (float)DD)));
    } else {
        int c = bid - 128;               // 0..99
        float n = (float)counts[c];
        float local = 0.f;
        for (int k = t; k < DD; k += 256) {
            float ta = srsa[k] * (R2a[(size_t)k * 128 + c] - n * smua[k]);
            float tb = srsb[k] * (R2b[(size_t)k * 128 + c] - n * smub[k]);
            local += ta * tb;
        }
        float s = block_reduce_sum_p(local, red);
        if (t == 0) {
            float add = s * (-2.0f / (float)DD);
            if (c == 0) {
                float t3 = 0.f;
                for (int cc = 0; cc < NC; cc++) {
                    float nc = (float)counts[cc];
                    t3 += nc * nc;
                }
                add += t3;
            }
            atomicAdd(out, add);
        }
    }
}

extern "C" void kernel_launch(void* const* d_in, const int* in_sizes, int n_in,
                              void* d_out, int out_size, void* d_ws, size_t ws_size,
                              hipStream_t stream) {
    const float* z_a = (const float*)d_in[0];
    const float* z_b = (const float*)d_in[1];
    const int* labels = (const int*)d_in[2];
    float* out = (float*)d_out;
    char* wsb = (char*)d_ws;

    float* Ga = (float*)(wsb + GA_B);
    float* Gb = (float*)(wsb + GB_B);
    float* R2a = (float*)(wsb + R2A_B);
    float* R2b = (float*)(wsb + R2B_B);
    int* counts = (int*)(wsb + CNT_B);
    short* XTa = (short*)(wsb + XTA_B);
    short* XTb = (short*)(wsb + XTB_B);
    short* MT = (short*)(wsb + MT_B);

    hipLaunchKernelGGL(k_prep, dim3(2257), dim3(256), 0, stream,
                       z_a, z_b, labels, XTa, XTb, MT,
                       (float*)(wsb + GA_B), counts, out);
    hipLaunchKernelGGL(k_gram, dim3(2 * NTILE * SPLITK), dim3(256), 0, stream,
                       XTa, XTb, MT, Ga, Gb, R2a, R2b);
    hipLaunchKernelGGL(k_term, dim3(228), dim3(256), 0, stream,
                       Ga, Gb, R2a, R2b, counts, out);
}

// Round 4
// 125.605 us; speedup vs baseline: 2.8259x; 1.1775x over previous
//
#include <hip/hip_runtime.h>
#include <math.h>

// ModifiedBarlowTwinsLoss — augmented-Gram formulation, bf16 MFMA.
// Y = [X | M] (M = one-hot labels, 128 padded classes). One MFMA pass gives:
//   X^T X  (10 upper 128x128 tiles)  -> Gram for term1 + column sumsq
//   X^T M  (4 tiles)                 -> per-class column sums R (term2)
// loss = (1/D^2) sum Ga~ Gb~ - (2/D) sum_c Sa~·Sb~ + sum_c n_c^2
//
// R4: 3 launches, no atomic Gram fold (R3's 7.3M cross-XCD atomics were the
// regression), no per-block stats recompute (R3's other regression).
//  - mu/var computed from the f32 INPUTS in k_prep (column partials via LDS
//    reduction, non-atomic global partial writes) — Gram no longer needed
//    for stats, and this matches the f32 reference more closely.
//  - k_gram: R1-proven part-store path + 2 tail blocks folding the column
//    partials into mu/rs (hidden under the 448 MFMA blocks).
//  - k_reduce: folds part for BOTH matrices per tile slice, applies stats in
//    registers, atomicAdds scalar loss. G/RT buffers eliminated entirely.
// Lessons: cg grid.sync ~50us/sync (R2). Cross-XCD atomic fold ruinous (R3).

#define NN 8192
#define DD 512
#define NC 100
#define SPLITK 16
#define NXT 10            // X^T X upper-triangle tiles
#define NTILE 14          // + 4 X^T M tiles

// ws byte offsets
#define CPS_B   0u           // cpsum [2][128 kb][512] f32 = 512 KB
#define CPQ_B   524288u      // cpsq  same = 512 KB
#define MUA_B   1048576u     // 512 f32
#define MUB_B   1050624u
#define RSA_B   1052672u
#define RSB_B   1054720u
#define CNT_B   1056768u     // 128 i32
#define XTA_B   4194304u     // 512*8192*2
#define XTB_B   12582912u
#define MT_B    20971520u    // 128*8192*2
#define PART_B  23068672u    // 2*14*16*16384*4 = 29,360,128 (end ~52.4 MB)

typedef __attribute__((ext_vector_type(8))) short short8;
typedef __attribute__((ext_vector_type(4))) float f32x4;

__constant__ int c_ti[NTILE] = {0,0,0,0,1,1,1,2,2,3, 0,1,2,3};
__constant__ int c_tj[NTILE] = {0,1,2,3,1,2,3,2,3,3, 4,4,4,4};
__constant__ float c_w[NXT]  = {1.f,2.f,2.f,2.f,1.f,2.f,2.f,1.f,2.f,1.f};

#if defined(__has_builtin)
#if __has_builtin(__builtin_amdgcn_global_load_lds)
#define HAVE_GLL 1
#endif
#endif

#ifdef HAVE_GLL
__device__ __forceinline__ void async16(const void* g, void* l) {
    __builtin_amdgcn_global_load_lds(
        (const __attribute__((address_space(1))) void*)g,
        (__attribute__((address_space(3))) void*)l, 16, 0, 0);
}
#endif

__device__ __forceinline__ short f2bf_rne(float f) {
    unsigned int u = __builtin_bit_cast(unsigned int, f);
    u += 0x7fffu + ((u >> 16) & 1u);
    return (short)(u >> 16);
}

__device__ __forceinline__ float block_reduce_sum_p(float v, float* red) {
    int lane = threadIdx.x & 63;
    int wave = threadIdx.x >> 6;
    #pragma unroll
    for (int off = 32; off > 0; off >>= 1) v += __shfl_down(v, off, 64);
    if (lane == 0) red[wave] = v;
    __syncthreads();
    float s = 0.f;
    if (threadIdx.x == 0) {
        int nw = (blockDim.x + 63) >> 6;
        for (int w = 0; w < nw; w++) s += red[w];
    }
    return s; // thread 0 only
}

// K1: blocks 0..2047 transpose-convert f32->bf16 + per-column {sum,sumsq}
//     partials; 2048..2175 one-hot MT; 2176 histogram + out-zero.
__global__ __launch_bounds__(256) void k_prep(const float* __restrict__ A,
                                              const float* __restrict__ B,
                                              const int* __restrict__ labels,
                                              short* __restrict__ XTa,
                                              short* __restrict__ XTb,
                                              short* __restrict__ MT,
                                              float* __restrict__ cpsum,
                                              float* __restrict__ cpsq,
                                              int* __restrict__ counts,
                                              float* __restrict__ out) {
    __shared__ short LT[64][72];
    __shared__ float cs[64], cq[64];
    __shared__ int hist[NC];
    int bid = blockIdx.x;
    int t = threadIdx.x;

    if (bid >= 2048) {
        if (bid >= 2176) {              // histogram + out zero
            if (t < NC) hist[t] = 0;
            __syncthreads();
            for (int i = t; i < NN; i += 256) atomicAdd(&hist[labels[i]], 1);
            __syncthreads();
            if (t < 128) counts[t] = (t < NC) ? hist[t] : 0;
            if (t == 0) out[0] = 0.f;
            return;
        }
        int c = bid - 2048;             // one-hot MT row
        unsigned short one = 0x3F80;    // bf16 1.0
        ushort4* dst = (ushort4*)(MT + (size_t)c * NN);
        const int4* lb4 = (const int4*)labels;
        #pragma unroll
        for (int j = 0; j < 8; j++) {
            int i4 = j * 256 + t;
            int4 lb = lb4[i4];
            ushort4 v;
            v.x = (lb.x == c) ? one : (unsigned short)0;
            v.y = (lb.y == c) ? one : (unsigned short)0;
            v.z = (lb.z == c) ? one : (unsigned short)0;
            v.w = (lb.w == c) ? one : (unsigned short)0;
            dst[i4] = v;
        }
        return;
    }

    int mat = bid >> 10;
    const float* X = mat ? B : A;
    short* XT = mat ? XTb : XTa;
    int rem = bid & 1023;
    int c0 = (rem >> 7) << 6;            // column block (8 of 64)
    int kb_blk = rem & 127;              // row block (128 of 64)
    int k0 = kb_blk << 6;
    int cc = t & 15;
    int kb = t >> 4;

    if (t < 64) { cs[t] = 0.f; cq[t] = 0.f; }
    __syncthreads();

    float4 ps = make_float4(0.f, 0.f, 0.f, 0.f);
    float4 pq = make_float4(0.f, 0.f, 0.f, 0.f);
    #pragma unroll
    for (int s = 0; s < 4; s++) {
        int kr = kb + s * 16;
        float4 v = *(const float4*)&X[(size_t)(k0 + kr) * DD + c0 + cc * 4];
        LT[cc * 4 + 0][kr] = f2bf_rne(v.x);
        LT[cc * 4 + 1][kr] = f2bf_rne(v.y);
        LT[cc * 4 + 2][kr] = f2bf_rne(v.z);
        LT[cc * 4 + 3][kr] = f2bf_rne(v.w);
        ps.x += v.x; ps.y += v.y; ps.z += v.z; ps.w += v.w;
        pq.x += v.x * v.x; pq.y += v.y * v.y;
        pq.z += v.z * v.z; pq.w += v.w * v.w;
    }
    atomicAdd(&cs[cc * 4 + 0], ps.x); atomicAdd(&cq[cc * 4 + 0], pq.x);
    atomicAdd(&cs[cc * 4 + 1], ps.y); atomicAdd(&cq[cc * 4 + 1], pq.y);
    atomicAdd(&cs[cc * 4 + 2], ps.z); atomicAdd(&cq[cc * 4 + 2], pq.z);
    atomicAdd(&cs[cc * 4 + 3], ps.w); atomicAdd(&cq[cc * 4 + 3], pq.w);
    __syncthreads();

    #pragma unroll
    for (int s = 0; s < 2; s++) {
        int idx = s * 256 + t;
        int orow = idx >> 3;
        int och = idx & 7;
        *(uint4*)&XT[(size_t)(c0 + orow) * NN + k0 + och * 8] =
            *(const uint4*)&LT[orow][och * 8];
    }
    if (t < 64) {
        size_t base = ((size_t)mat * 128 + kb_blk) * 512 + c0 + t;
        cpsum[base] = cs[t];
        cpsq[base] = cq[t];
    }
}

// K2: bf16 MFMA augmented Gram -> part (split-K partials, no atomics).
// 448 MFMA blocks + 2 stats blocks (fold column partials -> mu/rs, hidden
// under the MFMA blocks). Double-buffered LDS, XOR swizzle, XCD grouping.
__global__ __launch_bounds__(256, 2) void k_gram(const short* __restrict__ XTa,
                                                 const short* __restrict__ XTb,
                                                 const short* __restrict__ MT,
                                                 float* __restrict__ part,
                                                 const float* __restrict__ cpsum,
                                                 const float* __restrict__ cpsq,
                                                 float* __restrict__ mu_a,
                                                 float* __restrict__ mu_b,
                                                 float* __restrict__ rs_a,
                                                 float* __restrict__ rs_b) {
    __shared__ short LA[2][128 * 64];
    __shared__ short LB[2][128 * 64];

    int b = blockIdx.x;
    int t = threadIdx.x;

    if (b >= 448) {                      // stats fold (2 blocks)
        int mat = b - 448;
        for (int k = t; k < DD; k += 256) {
            float s = 0.f, q = 0.f;
            for (int kb = 0; kb < 128; kb++) {
                size_t base = ((size_t)mat * 128 + kb) * 512 + k;
                s += cpsum[base];
                q += cpsq[base];
            }
            float mu = s * (1.0f / (float)NN);
            float var = (q - (float)NN * mu * mu) / (float)(NN - 1);
            (mat ? mu_b : mu_a)[k] = mu;
            (mat ? rs_b : rs_a)[k] = rsqrtf(var);
        }
        return;
    }

    int xcd = b & 7;
    int idx = b >> 3;                    // 0..55
    int grp = (idx / NTILE) * 8 + xcd;   // (mat,chunk) group, 0..31
    int tile = idx % NTILE;
    int mat = grp >> 4;
    int chunk = grp & 15;

    const short* XT = mat ? XTb : XTa;
    int ti = c_ti[tile], tj = c_tj[tile];
    const short* PA = XT + (size_t)ti * 128 * NN;
    const short* PB = (tj < 4) ? (XT + (size_t)tj * 128 * NN) : MT;
    int k0 = chunk * (NN / SPLITK);

    int wave = t >> 6, lane = t & 63;
    int quad = lane >> 4, l16 = lane & 15;
    int x7 = l16 & 7;
    int wrow = (wave >> 1) * 64, wcol = (wave & 1) * 64;

    int srow = lane >> 3;                 // row within 8-row segment
    int sc = (lane & 7) ^ srow;           // swizzled global 16B-chunk index

    auto stage = [&](int buf, int kk) {
        #pragma unroll
        for (int rr = 0; rr < 4; rr++) {
            int seg = wave * 4 + rr;
            int row = seg * 8 + srow;
            const short* ga = PA + (size_t)row * NN + k0 + kk + sc * 8;
            const short* gb = PB + (size_t)row * NN + k0 + kk + sc * 8;
#ifdef HAVE_GLL
            async16(ga, &LA[buf][seg * 512]);
            async16(gb, &LB[buf][seg * 512]);
#else
            *(uint4*)&LA[buf][seg * 512 + lane * 8] = *(const uint4*)ga;
            *(uint4*)&LB[buf][seg * 512 + lane * 8] = *(const uint4*)gb;
#endif
        }
    };

    f32x4 acc[4][4];
    #pragma unroll
    for (int i = 0; i < 4; i++)
        #pragma unroll
        for (int j = 0; j < 4; j++) acc[i][j] = (f32x4)0.f;

    const int KR = NN / SPLITK;           // 512
    int cur = 0;
    stage(0, 0);
    __syncthreads();                      // drains vmcnt(0): buf0 ready

    for (int kk = 0; kk < KR; kk += 64) {
        if (kk + 64 < KR) stage(cur ^ 1, kk + 64);  // prefetch next step
        #pragma unroll
        for (int ks = 0; ks < 2; ks++) {
            short8 a[4], bfr[4];
            #pragma unroll
            for (int mt = 0; mt < 4; mt++)
                a[mt] = *(const short8*)&LA[cur][(wrow + mt * 16 + l16) * 64 +
                                                 (((ks * 4 + quad) ^ x7) << 3)];
            #pragma unroll
            for (int nt = 0; nt < 4; nt++)
                bfr[nt] = *(const short8*)&LB[cur][(wcol + nt * 16 + l16) * 64 +
                                                   (((ks * 4 + quad) ^ x7) << 3)];
            #pragma unroll
            for (int mt = 0; mt < 4; mt++)
                #pragma unroll
                for (int nt = 0; nt < 4; nt++)
                    acc[mt][nt] = __builtin_amdgcn_mfma_f32_16x16x32_bf16(
                        a[mt], bfr[nt], acc[mt][nt], 0, 0, 0);
        }
        __syncthreads();   // next buffer staged; cur reads done
        cur ^= 1;
    }

    float* pbase = part + ((size_t)(mat * NTILE + tile) * SPLITK + chunk) * 16384;
    #pragma unroll
    for (int mt = 0; mt < 4; mt++)
        #pragma unroll
        for (int nt = 0; nt < 4; nt++)
            #pragma unroll
            for (int rj = 0; rj < 4; rj++) {
                int rr2 = wrow + mt * 16 + quad * 4 + rj;
                int cc2 = wcol + nt * 16 + l16;
                pbase[rr2 * 128 + cc2] = acc[mt][nt][rj];
            }
}

// K3: fold part for BOTH matrices per slice, apply stats, accumulate loss.
// 224 blocks = 14 tiles x 16 slices. XX tiles -> term1; XM tiles -> term2;
// block 0 adds term3.
__global__ __launch_bounds__(256) void k_reduce(const float* __restrict__ part,
                                                const float* __restrict__ mu_a,
                                                const float* __restrict__ mu_b,
                                                const float* __restrict__ rs_a,
                                                const float* __restrict__ rs_b,
                                                const int* __restrict__ counts,
                                                float* __restrict__ out) {
    __shared__ float red[8];
    int bid = blockIdx.x;                // 0..223
    int tile = bid >> 4, sub = bid & 15;
    int t = threadIdx.x;
    int e4 = sub * 1024 + t * 4;

    const float4* pa = (const float4*)(part +
        ((size_t)tile * SPLITK) * 16384 + e4);
    const float4* pb = (const float4*)(part +
        ((size_t)(NTILE + tile) * SPLITK) * 16384 + e4);
    float4 Sa = make_float4(0.f, 0.f, 0.f, 0.f);
    float4 Sb = make_float4(0.f, 0.f, 0.f, 0.f);
    #pragma unroll
    for (int c = 0; c < SPLITK; c++) {
        float4 va = pa[(size_t)c * 4096];
        float4 vb = pb[(size_t)c * 4096];
        Sa.x += va.x; Sa.y += va.y; Sa.z += va.z; Sa.w += va.w;
        Sb.x += vb.x; Sb.y += vb.y; Sb.z += vb.z; Sb.w += vb.w;
    }

    int rw = e4 >> 7, cl = e4 & 127;
    float local = 0.f;
    float scale;
    if (tile < NXT) {
        int gi = c_ti[tile] * 128 + rw;
        int gj = c_tj[tile] * 128 + cl;
        float mai = mu_a[gi], rai = rs_a[gi];
        float mbi = mu_b[gi], rbi = rs_b[gi];
        float4 maj = *(const float4*)&mu_a[gj];
        float4 raj = *(const float4*)&rs_a[gj];
        float4 mbj = *(const float4*)&mu_b[gj];
        float4 rbj = *(const float4*)&rs_b[gj];
        float ga, gb;
        ga = rai * raj.x * (Sa.x - (float)NN * mai * maj.x);
        gb = rbi * rbj.x * (Sb.x - (float)NN * mbi * mbj.x);
        local += ga * gb;
        ga = rai * raj.y * (Sa.y - (float)NN * mai * maj.y);
        gb = rbi * rbj.y * (Sb.y - (float)NN * mbi * mbj.y);
        local += ga * gb;
        ga = rai * raj.z * (Sa.z - (float)NN * mai * maj.z);
        gb = rbi * rbj.z * (Sb.z - (float)NN * mbi * mbj.z);
        local += ga * gb;
        ga = rai * raj.w * (Sa.w - (float)NN * mai * maj.w);
        gb = rbi * rbj.w * (Sb.w - (float)NN * mbi * mbj.w);
        local += ga * gb;
        scale = c_w[tile] * (1.0f / ((float)DD * (float)DD));
    } else {
        int k = (tile - NXT) * 128 + rw;
        float mak = mu_a[k], rak = rs_a[k];
        float mbk = mu_b[k], rbk = rs_b[k];
        int4 cn = *(const int4*)&counts[cl];
        float ta, tb;
        ta = rak * (Sa.x - (float)cn.x * mak);
        tb = rbk * (Sb.x - (float)cn.x * mbk);
        local += ta * tb;
        ta = rak * (Sa.y - (float)cn.y * mak);
        tb = rbk * (Sb.y - (float)cn.y * mbk);
        local += ta * tb;
        ta = rak * (Sa.z - (float)cn.z * mak);
        tb = rbk * (Sb.z - (float)cn.z * mbk);
        local += ta * tb;
        ta = rak * (Sa.w - (float)cn.w * mak);
        tb = rbk * (Sb.w - (float)cn.w * mbk);
        local += ta * tb;
        scale = -2.0f / (float)DD;
    }

    float s = block_reduce_sum_p(local, red);
    if (t == 0) {
        float add = s * scale;
        if (bid == 0) {
            float t3 = 0.f;
            for (int cc2 = 0; cc2 < NC; cc2++) {
                float nc = (float)counts[cc2];
                t3 += nc * nc;
            }
            add += t3;
        }
        atomicAdd(out, add);
    }
}

extern "C" void kernel_launch(void* const* d_in, const int* in_sizes, int n_in,
                              void* d_out, int out_size, void* d_ws, size_t ws_size,
                              hipStream_t stream) {
    const float* z_a = (const float*)d_in[0];
    const float* z_b = (const float*)d_in[1];
    const int* labels = (const int*)d_in[2];
    float* out = (float*)d_out;
    char* wsb = (char*)d_ws;

    float* cpsum = (float*)(wsb + CPS_B);
    float* cpsq = (float*)(wsb + CPQ_B);
    float* mu_a = (float*)(wsb + MUA_B);
    float* mu_b = (float*)(wsb + MUB_B);
    float* rs_a = (float*)(wsb + RSA_B);
    float* rs_b = (float*)(wsb + RSB_B);
    int* counts = (int*)(wsb + CNT_B);
    short* XTa = (short*)(wsb + XTA_B);
    short* XTb = (short*)(wsb + XTB_B);
    short* MT = (short*)(wsb + MT_B);
    float* part = (float*)(wsb + PART_B);

    hipLaunchKernelGGL(k_prep, dim3(2177), dim3(256), 0, stream,
                       z_a, z_b, labels, XTa, XTb, MT, cpsum, cpsq, counts, out);
    hipLaunchKernelGGL(k_gram, dim3(450), dim3(256), 0, stream,
                       XTa, XTb, MT, part, cpsum, cpsq, mu_a, mu_b, rs_a, rs_b);
    hipLaunchKernelGGL(k_reduce, dim3(224), dim3(256), 0, stream,
                       part, mu_a, mu_b, rs_a, rs_b, counts, out);
}

// Round 5
// 110.333 us; speedup vs baseline: 3.2170x; 1.1384x over previous
//
#include <hip/hip_runtime.h>
#include <math.h>

// ModifiedBarlowTwinsLoss — augmented-Gram formulation, bf16 MFMA.
// Y = [X | M] (M = one-hot labels, 128 padded classes). One MFMA pass gives:
//   X^T X  (10 upper 128x128 tiles)  -> Gram for term1
//   X^T M  (4 tiles)                 -> per-class column sums R (term2)
// loss = (1/D^2) sum Ga~ Gb~ - (2/D) sum_c Sa~·Sb~ + sum_c n_c^2
//
// R5: isolate the R4 regression. Structure frozen at R4's 3 launches; only:
//  - k_prep stats: LDS float atomicAdd (suspected CAS-loop, 16-way same-addr
//    contention x 2048 blocks) REPLACED by shfl_xor wave fold + non-atomic
//    LDS partials. Zero atomics.
//  - k_reduce: 224 -> 448 blocks (>=1 block/CU for the latency-bound fold).
// Lessons: cg grid.sync ~50us/sync (R2). Cross-XCD atomic Gram fold ruinous
// (R3). LDS float atomics under contention suspected ruinous (R4, testing).

#define NN 8192
#define DD 512
#define NC 100
#define SPLITK 16
#define NXT 10            // X^T X upper-triangle tiles
#define NTILE 14          // + 4 X^T M tiles

// ws byte offsets
#define CPS_B   0u           // cpsum [2][128 kb][512] f32 = 512 KB
#define CPQ_B   524288u      // cpsq  same = 512 KB
#define MUA_B   1048576u     // 512 f32
#define MUB_B   1050624u
#define RSA_B   1052672u
#define RSB_B   1054720u
#define CNT_B   1056768u     // 128 i32
#define XTA_B   4194304u     // 512*8192*2
#define XTB_B   12582912u
#define MT_B    20971520u    // 128*8192*2
#define PART_B  23068672u    // 2*14*16*16384*4 = 29,360,128 (end ~52.4 MB)

typedef __attribute__((ext_vector_type(8))) short short8;
typedef __attribute__((ext_vector_type(4))) float f32x4;

__constant__ int c_ti[NTILE] = {0,0,0,0,1,1,1,2,2,3, 0,1,2,3};
__constant__ int c_tj[NTILE] = {0,1,2,3,1,2,3,2,3,3, 4,4,4,4};
__constant__ float c_w[NXT]  = {1.f,2.f,2.f,2.f,1.f,2.f,2.f,1.f,2.f,1.f};

#if defined(__has_builtin)
#if __has_builtin(__builtin_amdgcn_global_load_lds)
#define HAVE_GLL 1
#endif
#endif

#ifdef HAVE_GLL
__device__ __forceinline__ void async16(const void* g, void* l) {
    __builtin_amdgcn_global_load_lds(
        (const __attribute__((address_space(1))) void*)g,
        (__attribute__((address_space(3))) void*)l, 16, 0, 0);
}
#endif

__device__ __forceinline__ short f2bf_rne(float f) {
    unsigned int u = __builtin_bit_cast(unsigned int, f);
    u += 0x7fffu + ((u >> 16) & 1u);
    return (short)(u >> 16);
}

__device__ __forceinline__ float block_reduce_sum_p(float v, float* red) {
    int lane = threadIdx.x & 63;
    int wave = threadIdx.x >> 6;
    #pragma unroll
    for (int off = 32; off > 0; off >>= 1) v += __shfl_down(v, off, 64);
    if (lane == 0) red[wave] = v;
    __syncthreads();
    float s = 0.f;
    if (threadIdx.x == 0) {
        int nw = (blockDim.x + 63) >> 6;
        for (int w = 0; w < nw; w++) s += red[w];
    }
    return s; // thread 0 only
}

// K1: blocks 0..2047 transpose-convert f32->bf16 + per-column {sum,sumsq}
//     partials (shfl fold, no atomics); 2048..2175 one-hot MT;
//     2176 histogram + out-zero.
__global__ __launch_bounds__(256) void k_prep(const float* __restrict__ A,
                                              const float* __restrict__ B,
                                              const int* __restrict__ labels,
                                              short* __restrict__ XTa,
                                              short* __restrict__ XTb,
                                              short* __restrict__ MT,
                                              float* __restrict__ cpsum,
                                              float* __restrict__ cpsq,
                                              int* __restrict__ counts,
                                              float* __restrict__ out) {
    __shared__ short LT[64][72];
    __shared__ float WS[4][16][4];   // per-wave column-sum partials
    __shared__ float WQ[4][16][4];
    __shared__ int hist[NC];
    int bid = blockIdx.x;
    int t = threadIdx.x;

    if (bid >= 2048) {
        if (bid >= 2176) {              // histogram + out zero
            if (t < NC) hist[t] = 0;
            __syncthreads();
            for (int i = t; i < NN; i += 256) atomicAdd(&hist[labels[i]], 1);
            __syncthreads();
            if (t < 128) counts[t] = (t < NC) ? hist[t] : 0;
            if (t == 0) out[0] = 0.f;
            return;
        }
        int c = bid - 2048;             // one-hot MT row
        unsigned short one = 0x3F80;    // bf16 1.0
        ushort4* dst = (ushort4*)(MT + (size_t)c * NN);
        const int4* lb4 = (const int4*)labels;
        #pragma unroll
        for (int j = 0; j < 8; j++) {
            int i4 = j * 256 + t;
            int4 lb = lb4[i4];
            ushort4 v;
            v.x = (lb.x == c) ? one : (unsigned short)0;
            v.y = (lb.y == c) ? one : (unsigned short)0;
            v.z = (lb.z == c) ? one : (unsigned short)0;
            v.w = (lb.w == c) ? one : (unsigned short)0;
            dst[i4] = v;
        }
        return;
    }

    int mat = bid >> 10;
    const float* X = mat ? B : A;
    short* XT = mat ? XTb : XTa;
    int rem = bid & 1023;
    int c0 = (rem >> 7) << 6;            // column block
    int kb_blk = rem & 127;              // row block
    int k0 = kb_blk << 6;
    int cc = t & 15;
    int kb = t >> 4;

    float4 ps = make_float4(0.f, 0.f, 0.f, 0.f);
    float4 pq = make_float4(0.f, 0.f, 0.f, 0.f);
    #pragma unroll
    for (int s = 0; s < 4; s++) {
        int kr = kb + s * 16;
        float4 v = *(const float4*)&X[(size_t)(k0 + kr) * DD + c0 + cc * 4];
        LT[cc * 4 + 0][kr] = f2bf_rne(v.x);
        LT[cc * 4 + 1][kr] = f2bf_rne(v.y);
        LT[cc * 4 + 2][kr] = f2bf_rne(v.z);
        LT[cc * 4 + 3][kr] = f2bf_rne(v.w);
        ps.x += v.x; ps.y += v.y; ps.z += v.z; ps.w += v.w;
        pq.x += v.x * v.x; pq.y += v.y * v.y;
        pq.z += v.z * v.z; pq.w += v.w * v.w;
    }
    // wave fold: lanes {cc, cc+16, cc+32, cc+48} share columns
    #pragma unroll
    for (int off = 16; off <= 32; off <<= 1) {
        ps.x += __shfl_xor(ps.x, off, 64); pq.x += __shfl_xor(pq.x, off, 64);
        ps.y += __shfl_xor(ps.y, off, 64); pq.y += __shfl_xor(pq.y, off, 64);
        ps.z += __shfl_xor(ps.z, off, 64); pq.z += __shfl_xor(pq.z, off, 64);
        ps.w += __shfl_xor(ps.w, off, 64); pq.w += __shfl_xor(pq.w, off, 64);
    }
    int wv = t >> 6, lane = t & 63;
    if (lane < 16) {
        WS[wv][lane][0] = ps.x; WS[wv][lane][1] = ps.y;
        WS[wv][lane][2] = ps.z; WS[wv][lane][3] = ps.w;
        WQ[wv][lane][0] = pq.x; WQ[wv][lane][1] = pq.y;
        WQ[wv][lane][2] = pq.z; WQ[wv][lane][3] = pq.w;
    }
    __syncthreads();

    #pragma unroll
    for (int s = 0; s < 2; s++) {
        int idx = s * 256 + t;
        int orow = idx >> 3;
        int och = idx & 7;
        *(uint4*)&XT[(size_t)(c0 + orow) * NN + k0 + och * 8] =
            *(const uint4*)&LT[orow][och * 8];
    }
    if (t < 64) {
        int ccf = t >> 2, j = t & 3;
        float s = WS[0][ccf][j] + WS[1][ccf][j] + WS[2][ccf][j] + WS[3][ccf][j];
        float q = WQ[0][ccf][j] + WQ[1][ccf][j] + WQ[2][ccf][j] + WQ[3][ccf][j];
        size_t base = ((size_t)mat * 128 + kb_blk) * 512 + c0 + t;
        cpsum[base] = s;
        cpsq[base] = q;
    }
}

// K2: bf16 MFMA augmented Gram -> part (split-K partials, no atomics).
// 448 MFMA blocks + 2 stats blocks (fold column partials -> mu/rs, hidden
// under the MFMA blocks). Double-buffered LDS, XOR swizzle, XCD grouping.
__global__ __launch_bounds__(256, 2) void k_gram(const short* __restrict__ XTa,
                                                 const short* __restrict__ XTb,
                                                 const short* __restrict__ MT,
                                                 float* __restrict__ part,
                                                 const float* __restrict__ cpsum,
                                                 const float* __restrict__ cpsq,
                                                 float* __restrict__ mu_a,
                                                 float* __restrict__ mu_b,
                                                 float* __restrict__ rs_a,
                                                 float* __restrict__ rs_b) {
    __shared__ short LA[2][128 * 64];
    __shared__ short LB[2][128 * 64];

    int b = blockIdx.x;
    int t = threadIdx.x;

    if (b >= 448) {                      // stats fold (2 blocks)
        int mat = b - 448;
        for (int k = t; k < DD; k += 256) {
            float s = 0.f, q = 0.f;
            for (int kb = 0; kb < 128; kb++) {
                size_t base = ((size_t)mat * 128 + kb) * 512 + k;
                s += cpsum[base];
                q += cpsq[base];
            }
            float mu = s * (1.0f / (float)NN);
            float var = (q - (float)NN * mu * mu) / (float)(NN - 1);
            (mat ? mu_b : mu_a)[k] = mu;
            (mat ? rs_b : rs_a)[k] = rsqrtf(var);
        }
        return;
    }

    int xcd = b & 7;
    int idx = b >> 3;                    // 0..55
    int grp = (idx / NTILE) * 8 + xcd;   // (mat,chunk) group, 0..31
    int tile = idx % NTILE;
    int mat = grp >> 4;
    int chunk = grp & 15;

    const short* XT = mat ? XTb : XTa;
    int ti = c_ti[tile], tj = c_tj[tile];
    const short* PA = XT + (size_t)ti * 128 * NN;
    const short* PB = (tj < 4) ? (XT + (size_t)tj * 128 * NN) : MT;
    int k0 = chunk * (NN / SPLITK);

    int wave = t >> 6, lane = t & 63;
    int quad = lane >> 4, l16 = lane & 15;
    int x7 = l16 & 7;
    int wrow = (wave >> 1) * 64, wcol = (wave & 1) * 64;

    int srow = lane >> 3;                 // row within 8-row segment
    int sc = (lane & 7) ^ srow;           // swizzled global 16B-chunk index

    auto stage = [&](int buf, int kk) {
        #pragma unroll
        for (int rr = 0; rr < 4; rr++) {
            int seg = wave * 4 + rr;
            int row = seg * 8 + srow;
            const short* ga = PA + (size_t)row * NN + k0 + kk + sc * 8;
            const short* gb = PB + (size_t)row * NN + k0 + kk + sc * 8;
#ifdef HAVE_GLL
            async16(ga, &LA[buf][seg * 512]);
            async16(gb, &LB[buf][seg * 512]);
#else
            *(uint4*)&LA[buf][seg * 512 + lane * 8] = *(const uint4*)ga;
            *(uint4*)&LB[buf][seg * 512 + lane * 8] = *(const uint4*)gb;
#endif
        }
    };

    f32x4 acc[4][4];
    #pragma unroll
    for (int i = 0; i < 4; i++)
        #pragma unroll
        for (int j = 0; j < 4; j++) acc[i][j] = (f32x4)0.f;

    const int KR = NN / SPLITK;           // 512
    int cur = 0;
    stage(0, 0);
    __syncthreads();                      // drains vmcnt(0): buf0 ready

    for (int kk = 0; kk < KR; kk += 64) {
        if (kk + 64 < KR) stage(cur ^ 1, kk + 64);  // prefetch next step
        #pragma unroll
        for (int ks = 0; ks < 2; ks++) {
            short8 a[4], bfr[4];
            #pragma unroll
            for (int mt = 0; mt < 4; mt++)
                a[mt] = *(const short8*)&LA[cur][(wrow + mt * 16 + l16) * 64 +
                                                 (((ks * 4 + quad) ^ x7) << 3)];
            #pragma unroll
            for (int nt = 0; nt < 4; nt++)
                bfr[nt] = *(const short8*)&LB[cur][(wcol + nt * 16 + l16) * 64 +
                                                   (((ks * 4 + quad) ^ x7) << 3)];
            #pragma unroll
            for (int mt = 0; mt < 4; mt++)
                #pragma unroll
                for (int nt = 0; nt < 4; nt++)
                    acc[mt][nt] = __builtin_amdgcn_mfma_f32_16x16x32_bf16(
                        a[mt], bfr[nt], acc[mt][nt], 0, 0, 0);
        }
        __syncthreads();   // next buffer staged; cur reads done
        cur ^= 1;
    }

    float* pbase = part + ((size_t)(mat * NTILE + tile) * SPLITK + chunk) * 16384;
    #pragma unroll
    for (int mt = 0; mt < 4; mt++)
        #pragma unroll
        for (int nt = 0; nt < 4; nt++)
            #pragma unroll
            for (int rj = 0; rj < 4; rj++) {
                int rr2 = wrow + mt * 16 + quad * 4 + rj;
                int cc2 = wcol + nt * 16 + l16;
                pbase[rr2 * 128 + cc2] = acc[mt][nt][rj];
            }
}

// K3: fold part for BOTH matrices per slice, apply stats, accumulate loss.
// 448 blocks = 14 tiles x 32 slices (>=1 block/CU). XX -> term1; XM -> term2;
// block 0 adds term3.
__global__ __launch_bounds__(256) void k_reduce(const float* __restrict__ part,
                                                const float* __restrict__ mu_a,
                                                const float* __restrict__ mu_b,
                                                const float* __restrict__ rs_a,
                                                const float* __restrict__ rs_b,
                                                const int* __restrict__ counts,
                                                float* __restrict__ out) {
    __shared__ float red[8];
    int bid = blockIdx.x;                // 0..447
    int tile = bid >> 5, sub = bid & 31;
    int t = threadIdx.x;
    int e2 = sub * 512 + t * 2;

    const float2* pa = (const float2*)(part +
        ((size_t)tile * SPLITK) * 16384 + e2);
    const float2* pb = (const float2*)(part +
        ((size_t)(NTILE + tile) * SPLITK) * 16384 + e2);
    float2 Sa = make_float2(0.f, 0.f);
    float2 Sb = make_float2(0.f, 0.f);
    #pragma unroll
    for (int c = 0; c < SPLITK; c++) {
        float2 va = pa[(size_t)c * 8192];
        float2 vb = pb[(size_t)c * 8192];
        Sa.x += va.x; Sa.y += va.y;
        Sb.x += vb.x; Sb.y += vb.y;
    }

    int rw = e2 >> 7, cl = e2 & 127;
    float local = 0.f;
    float scale;
    if (tile < NXT) {
        int gi = c_ti[tile] * 128 + rw;
        int gj = c_tj[tile] * 128 + cl;
        float mai = mu_a[gi], rai = rs_a[gi];
        float mbi = mu_b[gi], rbi = rs_b[gi];
        float2 maj = *(const float2*)&mu_a[gj];
        float2 raj = *(const float2*)&rs_a[gj];
        float2 mbj = *(const float2*)&mu_b[gj];
        float2 rbj = *(const float2*)&rs_b[gj];
        float ga, gb;
        ga = rai * raj.x * (Sa.x - (float)NN * mai * maj.x);
        gb = rbi * rbj.x * (Sb.x - (float)NN * mbi * mbj.x);
        local += ga * gb;
        ga = rai * raj.y * (Sa.y - (float)NN * mai * maj.y);
        gb = rbi * rbj.y * (Sb.y - (float)NN * mbi * mbj.y);
        local += ga * gb;
        scale = c_w[tile] * (1.0f / ((float)DD * (float)DD));
    } else {
        int k = (tile - NXT) * 128 + rw;
        float mak = mu_a[k], rak = rs_a[k];
        float mbk = mu_b[k], rbk = rs_b[k];
        int2 cn = *(const int2*)&counts[cl];
        float ta, tb;
        ta = rak * (Sa.x - (float)cn.x * mak);
        tb = rbk * (Sb.x - (float)cn.x * mbk);
        local += ta * tb;
        ta = rak * (Sa.y - (float)cn.y * mak);
        tb = rbk * (Sb.y - (float)cn.y * mbk);
        local += ta * tb;
        scale = -2.0f / (float)DD;
    }

    float s = block_reduce_sum_p(local, red);
    if (t == 0) {
        float add = s * scale;
        if (bid == 0) {
            float t3 = 0.f;
            for (int cc2 = 0; cc2 < NC; cc2++) {
                float nc = (float)counts[cc2];
                t3 += nc * nc;
            }
            add += t3;
        }
        atomicAdd(out, add);
    }
}

extern "C" void kernel_launch(void* const* d_in, const int* in_sizes, int n_in,
                              void* d_out, int out_size, void* d_ws, size_t ws_size,
                              hipStream_t stream) {
    const float* z_a = (const float*)d_in[0];
    const float* z_b = (const float*)d_in[1];
    const int* labels = (const int*)d_in[2];
    float* out = (float*)d_out;
    char* wsb = (char*)d_ws;

    float* cpsum = (float*)(wsb + CPS_B);
    float* cpsq = (float*)(wsb + CPQ_B);
    float* mu_a = (float*)(wsb + MUA_B);
    float* mu_b = (float*)(wsb + MUB_B);
    float* rs_a = (float*)(wsb + RSA_B);
    float* rs_b = (float*)(wsb + RSB_B);
    int* counts = (int*)(wsb + CNT_B);
    short* XTa = (short*)(wsb + XTA_B);
    short* XTb = (short*)(wsb + XTB_B);
    short* MT = (short*)(wsb + MT_B);
    float* part = (float*)(wsb + PART_B);

    hipLaunchKernelGGL(k_prep, dim3(2177), dim3(256), 0, stream,
                       z_a, z_b, labels, XTa, XTb, MT, cpsum, cpsq, counts, out);
    hipLaunchKernelGGL(k_gram, dim3(450), dim3(256), 0, stream,
                       XTa, XTb, MT, part, cpsum, cpsq, mu_a, mu_b, rs_a, rs_b);
    hipLaunchKernelGGL(k_reduce, dim3(448), dim3(256), 0, stream,
                       part, mu_a, mu_b, rs_a, rs_b, counts, out);
}